// Round 6
// baseline (581.134 us; speedup 1.0000x reference)
//
#include <hip/hip_runtime.h>

// GraphConvGRU: B=16384, IN=32, HID=3, N=22 nodes, T=100 steps.
// Graph collapses to 3 node-equivalence classes -> per-chain state is 9 floats,
// 22x22 normalized adjacency reduces exactly to 3x3 (verified; R0-R3 passed,
// absmax 3.9e-3).
//
// R5 = R4 resubmission (container died before benching R4), hardened:
//   - ws_size guard: two-kernel path needs 78.6MB of d_ws; if unavailable,
//     fall back to the R3 fused kernel (constant decision -> graph-safe).
// R4 rationale: fused variants R1-R3 all ~200us regardless of store schedule
//   (1-wave/SIMD compute phase-locked with store bursts, no TLP).
//   K1: 256 blocks x 64 thr, no replication, writes compact states
//       [b][t*12+q] (78.6MB) to d_ws via LDS transpose, coalesced f4.
//   K2: 1024 blocks x 256 thr (4 waves/SIMD, fill-like regime = 5.9TB/s
//       proven), gathers from L3-resident compact, streams 432MB coalesced.

#define TPB1 64
#define GRID1 (16384 / TPB1)        // 256 blocks, 1 wave/CU
#define T_TOTAL 100
#define SCH 10                      // steps per chunk
#define NCHUNK (T_TOTAL / SCH)      // 10
#define REC 12                      // floats per (b,t) record (9 used, 3 pad)
#define ROWF (T_TOTAL * REC)        // 1200 floats per b-row of compact
#define ROWF4 (ROWF / 4)            // 300 f4
#define CH_F4 (SCH * REC / 4)       // 30 f4 per (row, chunk)
#define K1_ITERS 30                 // (TPB1*CH_F4)/TPB1

#define TPB2 256
#define BPB2 16                     // b-rows per K2 block
#define GRID2 (16384 / BPB2)        // 1024 blocks
#define OUT_ROW_F4 1650             // 6600 floats per output row
#define OUT_ELEMS 6600

// fused-fallback geometry (R3)
#define FREP 4
#define FRPW 16
#define FGRID (16384 / TPB1 * FREP) // 1024 blocks
#define FROW_F4 (SCH * 66 / 4)      // 165
#define FSTRIDE (SCH * 9 + 1)       // 91
#define FSTG (TPB1 * FSTRIDE)       // 5824 floats
#define F4_PER_REP (FRPW * FROW_F4) // 2640
#define FGITERS ((F4_PER_REP + TPB1 - 1) / TPB1)  // 42

#if __has_builtin(__builtin_amdgcn_exp2f)
#define EXP2F __builtin_amdgcn_exp2f
#else
#define EXP2F exp2f
#endif
#if __has_builtin(__builtin_amdgcn_rcpf)
#define RCPF __builtin_amdgcn_rcpf
#else
#define RCPF(x) (1.0f / (x))
#endif

static __device__ __forceinline__ float fast_sigmoid(float x) {
    float e = EXP2F(-1.44269504f * x);
    return RCPF(1.0f + e);
}
static __device__ __forceinline__ float fast_tanh(float x) {
    float e = EXP2F(2.88539008f * x);          // exp(2x)
    return 1.0f - 2.0f * RCPF(1.0f + e);
}

// cls3[k] = class(node k/3)*3 + k%3 for k in [0,66)
__device__ const unsigned char d_cls3[66] = {
    0,1,2, 3,4,5, 3,4,5, 6,7,8, 3,4,5, 3,4,5, 6,7,8, 3,4,5, 3,4,5,
    0,1,2, 3,4,5, 3,4,5, 6,7,8, 3,4,5, 3,4,5, 6,7,8, 3,4,5, 3,4,5,
    3,4,5, 3,4,5, 3,4,5, 3,4,5
};

// ---- shared device helpers: weight staging + projections + recurrence ----
struct GruConsts {
    float xr[3], xz[3], xh[3];
    float W9[9], gb3[3];
};

static __device__ __forceinline__ void load_consts_and_project(
    const float* __restrict__ x, int b,
    const float* __restrict__ wS,   // 297 staged floats
    const float* __restrict__ gwS, const float* __restrict__ gbS,
    GruConsts& C)
{
    float xv[32];
    const float4* xp = reinterpret_cast<const float4*>(x + (size_t)b * 32);
    #pragma unroll
    for (int i = 0; i < 8; ++i) {
        float4 v = xp[i];
        xv[4*i+0] = v.x; xv[4*i+1] = v.y; xv[4*i+2] = v.z; xv[4*i+3] = v.w;
    }
    #pragma unroll
    for (int j = 0; j < 3; ++j) { C.xr[j] = wS[288+j]; C.xz[j] = wS[291+j]; C.xh[j] = wS[294+j]; }
    #pragma unroll
    for (int i = 0; i < 32; ++i) {
        float xi = xv[i];
        #pragma unroll
        for (int j = 0; j < 3; ++j) {
            C.xr[j] = fmaf(xi, wS[i*3+j],       C.xr[j]);
            C.xz[j] = fmaf(xi, wS[96 + i*3+j],  C.xz[j]);
            C.xh[j] = fmaf(xi, wS[192 + i*3+j], C.xh[j]);
        }
    }
    #pragma unroll
    for (int i = 0; i < 9; ++i) C.W9[i] = gwS[i];
    #pragma unroll
    for (int j = 0; j < 3; ++j) C.gb3[j] = gbS[j];
}

static __device__ __forceinline__ void gru_step(float* __restrict__ h, const GruConsts& C)
{
    // reduced symmetric-normalized adjacency (3 classes), exact:
    const float M00 = 0.0769230769f;   // 1/13
    const float M01 = 1.1094003925f;   // 4/sqrt(13)
    const float M02 = 0.4961389384f;   // 4/sqrt(65)
    const float M10 = 0.1386750491f;   // 1/(2 sqrt(13))
    const float M11 = 0.75f;
    const float M20 = 0.2480694691f;   // 2/sqrt(65)
    const float M22 = 0.6f;

    float mh[9], gh[9];
    #pragma unroll
    for (int j = 0; j < 3; ++j) {
        mh[j]     = M00 * h[j] + M01 * h[3+j] + M02 * h[6+j];
        mh[3 + j] = M10 * h[j] + M11 * h[3+j];
        mh[6 + j] = M20 * h[j] + M22 * h[6+j];
    }
    #pragma unroll
    for (int c = 0; c < 3; ++c)
        #pragma unroll
        for (int j = 0; j < 3; ++j)
            gh[c*3+j] = C.gb3[j] + mh[c*3+0]*C.W9[j] + mh[c*3+1]*C.W9[3+j] + mh[c*3+2]*C.W9[6+j];
    #pragma unroll
    for (int c = 0; c < 3; ++c) {
        #pragma unroll
        for (int j = 0; j < 3; ++j) {
            float g  = gh[c*3+j];
            float r  = fast_sigmoid(C.xr[j] + g);
            float z  = fast_sigmoid(C.xz[j] + g);
            float ht = fast_tanh(C.xh[j] + r * g);
            float hv = h[c*3+j];
            h[c*3+j] = hv + z * (ht - hv);
        }
    }
}

static __device__ __forceinline__ void stage_weights(
    int tid, int stride,
    const float* __restrict__ w_r_W, const float* __restrict__ w_r_b,
    const float* __restrict__ w_z_W, const float* __restrict__ w_z_b,
    const float* __restrict__ w_h_W, const float* __restrict__ w_h_b,
    const float* __restrict__ gcn_W, const float* __restrict__ gcn_b,
    float* __restrict__ wS, float* __restrict__ gwS, float* __restrict__ gbS)
{
    for (int i = tid; i < 96; i += stride) {
        wS[i]       = w_r_W[i];
        wS[96 + i]  = w_z_W[i];
        wS[192 + i] = w_h_W[i];
    }
    if (tid < 3) {
        wS[288 + tid] = w_r_b[tid];
        wS[291 + tid] = w_z_b[tid];
        wS[294 + tid] = w_h_b[tid];
        gbS[tid] = gcn_b[tid];
    }
    if (tid < 9) gwS[tid] = gcn_W[tid];
}

// ---------------- K1: recurrence -> compact states ----------------
__global__ __launch_bounds__(TPB1) void gcgru_compute(
    const float* __restrict__ x,
    const float* __restrict__ w_r_W, const float* __restrict__ w_r_b,
    const float* __restrict__ w_z_W, const float* __restrict__ w_z_b,
    const float* __restrict__ w_h_W, const float* __restrict__ w_h_b,
    const float* __restrict__ gcn_W, const float* __restrict__ gcn_b,
    float* __restrict__ compact)
{
    __shared__ float wS[297];
    __shared__ float gwS[9];
    __shared__ float gbS[3];
    __shared__ float stage[TPB1 * SCH * REC];   // 64 x 120 floats = 30.7 KB

    const int tid = threadIdx.x;
    const int b0  = blockIdx.x * TPB1;

    stage_weights(tid, TPB1, w_r_W, w_r_b, w_z_W, w_z_b, w_h_W, w_h_b,
                  gcn_W, gcn_b, wS, gwS, gbS);
    // single wave: DS pipe in-order, no barrier needed (validated R3)

    GruConsts C;
    load_consts_and_project(x, b0 + tid, wS, gwS, gbS, C);

    float h[9];
    #pragma unroll
    for (int i = 0; i < 9; ++i) h[i] = 0.0f;

    float4* cmp4 = reinterpret_cast<float4*>(compact);

    for (int chunk = 0; chunk < NCHUNK; ++chunk) {
        float* stw = stage + tid * (SCH * REC);

        #pragma unroll
        for (int s = 0; s < SCH; ++s) {
            gru_step(h, C);
            #pragma unroll
            for (int q = 0; q < 9; ++q) stw[s*REC + q] = h[q];
            stw[s*REC + 9] = 0.0f; stw[s*REC + 10] = 0.0f; stw[s*REC + 11] = 0.0f;
        }

        // cooperative coalesced f4 store of this chunk's 64x30 f4 records
        const int cbase = chunk * CH_F4;
        #pragma unroll
        for (int i = 0; i < K1_ITERS; ++i) {
            int f  = i * TPB1 + tid;          // 0..1919
            int rl = f / CH_F4;               // 0..63
            int j4 = f - rl * CH_F4;          // 0..29
            const float4* srow = reinterpret_cast<const float4*>(stage + rl * (SCH * REC));
            cmp4[(size_t)(b0 + rl) * ROWF4 + cbase + j4] = srow[j4];
        }
        // single wave: in-order DS orders next chunk's writes after these reads
    }
}

// ---------------- K2: expand compact -> full output ----------------
__global__ __launch_bounds__(TPB2) void gcgru_expand(
    const float* __restrict__ compact,
    float* __restrict__ out)
{
    __shared__ unsigned short tabE[OUT_ELEMS];   // 6600 x u16 = 13.2 KB

    const int tid = threadIdx.x;
    const int b0  = blockIdx.x * BPB2;

    for (int jj = tid; jj < OUT_ELEMS; jj += TPB2) {
        int t = jj / 66;
        int k = jj - 66 * t;
        tabE[jj] = (unsigned short)(t * REC + d_cls3[k]);
    }
    __syncthreads();

    float4* out4 = reinterpret_cast<float4*>(out);

    for (int r = 0; r < BPB2; ++r) {
        const float* cp = compact + (size_t)(b0 + r) * ROWF;
        float4* orow = out4 + (size_t)(b0 + r) * OUT_ROW_F4;
        for (int j4 = tid; j4 < OUT_ROW_F4; j4 += TPB2) {
            int jj = 4 * j4;
            float4 v;
            v.x = cp[tabE[jj + 0]];
            v.y = cp[tabE[jj + 1]];
            v.z = cp[tabE[jj + 2]];
            v.w = cp[tabE[jj + 3]];
            orow[j4] = v;
        }
    }
}

// ---------------- fused fallback (R3) if ws too small ----------------
__global__ __launch_bounds__(TPB1) void gcgru_fused(
    const float* __restrict__ x,
    const float* __restrict__ w_r_W, const float* __restrict__ w_r_b,
    const float* __restrict__ w_z_W, const float* __restrict__ w_z_b,
    const float* __restrict__ w_h_W, const float* __restrict__ w_h_b,
    const float* __restrict__ gcn_W, const float* __restrict__ gcn_b,
    float* __restrict__ out)
{
    __shared__ float wS[297];
    __shared__ float gwS[9];
    __shared__ float gbS[3];
    __shared__ unsigned int tabS[FROW_F4];
    __shared__ float stage[FSTG];

    const int tid = threadIdx.x;
    const int rep = blockIdx.x & (FREP - 1);
    const int b0  = (blockIdx.x >> 2) * TPB1;
    const int row0 = rep * FRPW;

    stage_weights(tid, TPB1, w_r_W, w_r_b, w_z_W, w_z_b, w_h_W, w_h_b,
                  gcn_W, gcn_b, wS, gwS, gbS);
    for (int j4 = tid; j4 < FROW_F4; j4 += TPB1) {
        unsigned int w = 0;
        #pragma unroll
        for (int u = 0; u < 4; ++u) {
            int jj = 4 * j4 + u;
            int tl = jj / 66;
            int k  = jj - 66 * tl;
            w |= (unsigned int)(tl * 9 + d_cls3[k]) << (8 * u);
        }
        tabS[j4] = w;
    }

    GruConsts C;
    load_consts_and_project(x, b0 + tid, wS, gwS, gbS, C);

    float h[9];
    #pragma unroll
    for (int i = 0; i < 9; ++i) h[i] = 0.0f;

    float4* out4 = reinterpret_cast<float4*>(out);

    for (int chunk = 0; chunk < NCHUNK; ++chunk) {
        float* stw = stage + tid * FSTRIDE;
        #pragma unroll
        for (int s = 0; s < SCH; ++s) {
            gru_step(h, C);
            #pragma unroll
            for (int q = 0; q < 9; ++q) stw[s*9 + q] = h[q];
        }
        const int cbase = chunk * FROW_F4;
        for (int i = 0; i < FGITERS; ++i) {
            int f = i * TPB1 + tid;
            if (f < F4_PER_REP) {
                int rl = f / FROW_F4;
                int j4 = f - rl * FROW_F4;
                int r  = row0 + rl;
                unsigned int tw = tabS[j4];
                const float* row = stage + r * FSTRIDE;
                float4 v;
                v.x = row[tw & 255u];
                v.y = row[(tw >> 8)  & 255u];
                v.z = row[(tw >> 16) & 255u];
                v.w = row[tw >> 24];
                out4[(size_t)(b0 + r) * OUT_ROW_F4 + cbase + j4] = v;
            }
        }
    }
}

extern "C" void kernel_launch(void* const* d_in, const int* in_sizes, int n_in,
                              void* d_out, int out_size, void* d_ws, size_t ws_size,
                              hipStream_t stream) {
    const float* xp     = (const float*)d_in[0];
    const float* w_r_W  = (const float*)d_in[1];
    const float* w_r_b  = (const float*)d_in[2];
    const float* w_z_W  = (const float*)d_in[3];
    const float* w_z_b  = (const float*)d_in[4];
    const float* w_h_W  = (const float*)d_in[5];
    const float* w_h_b  = (const float*)d_in[6];
    const float* gcn_W  = (const float*)d_in[7];
    const float* gcn_b  = (const float*)d_in[8];
    float* outp = (float*)d_out;

    const size_t need = (size_t)16384 * ROWF * sizeof(float);   // 78.6 MB
    if (ws_size >= need && d_ws != nullptr) {
        float* compact = (float*)d_ws;
        gcgru_compute<<<GRID1, TPB1, 0, stream>>>(xp, w_r_W, w_r_b, w_z_W, w_z_b,
                                                  w_h_W, w_h_b, gcn_W, gcn_b, compact);
        gcgru_expand<<<GRID2, TPB2, 0, stream>>>(compact, outp);
    } else {
        gcgru_fused<<<FGRID, TPB1, 0, stream>>>(xp, w_r_W, w_r_b, w_z_W, w_z_b,
                                                w_h_W, w_h_b, gcn_W, gcn_b, outp);
    }
}

// Round 7
// 497.540 us; speedup vs baseline: 1.1680x; 1.1680x over previous
//
#include <hip/hip_runtime.h>

// GraphConvGRU: B=16384, IN=32, HID=3, N=22 nodes, T=100 steps.
// Graph collapses to 3 node-equivalence classes -> per-chain state = 9 floats,
// reduced 3x3 adjacency (verified; R0-R3,R6 passed, absmax 3.9e-3).
//
// R7 theory: store-data VGPR hold-time caps in-flight store bytes.
//   Fill saturates (6 TB/s) because constant data regs -> no vmcnt recycling
//   -> ~63 stores in flight. Our gather->store loops recycle 2-4 data quads
//   -> ~3KB in flight/wave; 4 waves/CU * 3KB / RTT(~3300cy) = 2.2 TB/s =
//   exactly R1/R2/R3/K2's observed plateau, schedule-independent.
// Fix: in-flight bytes/CU = waves * Q * 1KB >= ~40KB:
//   - REP 4->8: 2048 blocks x 64thr = 8 waves/CU (LDS 9.5KB -> 8 blk/CU fit)
//   - batched expansion: gather 9 f4 into static reg array, then 9
//     back-to-back stores (Q~9). 8 waves x 9KB = 72KB in flight.

#define TPB 64
#define REP 8
#define RPW (TPB / REP)             // 8 rows stored per replica
#define NGRP (16384 / TPB)          // 256 chain-groups
#define GRID (NGRP * REP)           // 2048 blocks
#define T_TOTAL 100
#define SCH 4                       // steps per chunk
#define NCHUNK (T_TOTAL / SCH)      // 25
#define ROW_F4 (SCH * 66 / 4)       // 66 f4 per (row, chunk)
#define STG_STRIDE (SCH * 9 + 1)    // 37 floats per thread-row (odd: 2 lanes/bank)
#define STG_SZ (TPB * STG_STRIDE)   // 2368 floats = 9.25 KB
#define F4_PER_REP (RPW * ROW_F4)   // 528 f4 per replica per chunk
#define GITERS ((F4_PER_REP + TPB - 1) / TPB)   // 9
#define OUT_ROW_F4 1650

#if __has_builtin(__builtin_amdgcn_exp2f)
#define EXP2F __builtin_amdgcn_exp2f
#else
#define EXP2F exp2f
#endif
#if __has_builtin(__builtin_amdgcn_rcpf)
#define RCPF __builtin_amdgcn_rcpf
#else
#define RCPF(x) (1.0f / (x))
#endif

static __device__ __forceinline__ float fast_sigmoid(float x) {
    float e = EXP2F(-1.44269504f * x);
    return RCPF(1.0f + e);
}
static __device__ __forceinline__ float fast_tanh(float x) {
    float e = EXP2F(2.88539008f * x);          // exp(2x)
    return 1.0f - 2.0f * RCPF(1.0f + e);
}

// cls3[k] = class(node k/3)*3 + k%3 for k in [0,66)
__device__ const unsigned char d_cls3[66] = {
    0,1,2, 3,4,5, 3,4,5, 6,7,8, 3,4,5, 3,4,5, 6,7,8, 3,4,5, 3,4,5,
    0,1,2, 3,4,5, 3,4,5, 6,7,8, 3,4,5, 3,4,5, 6,7,8, 3,4,5, 3,4,5,
    3,4,5, 3,4,5, 3,4,5, 3,4,5
};

__global__ __launch_bounds__(TPB) void gcgru_fused(
    const float* __restrict__ x,
    const float* __restrict__ w_r_W, const float* __restrict__ w_r_b,
    const float* __restrict__ w_z_W, const float* __restrict__ w_z_b,
    const float* __restrict__ w_h_W, const float* __restrict__ w_h_b,
    const float* __restrict__ gcn_W, const float* __restrict__ gcn_b,
    float* __restrict__ out)
{
    __shared__ float stage[STG_SZ];         // weights during init, then states
    __shared__ unsigned int tabS[ROW_F4];   // 66 packed per-f4 state indices

    const int tid  = threadIdx.x;           // 0..63, chain within group
    const int rep  = blockIdx.x & (REP - 1);
    const int b0   = (blockIdx.x >> 3) * TPB;
    const int row0 = rep * RPW;             // first row this replica stores

    // ---- init: weights into stage[0..287] (aliased; overwritten after projection) ----
    for (int i = tid; i < 96; i += TPB) {
        stage[i]       = w_r_W[i];
        stage[96 + i]  = w_z_W[i];
        stage[192 + i] = w_h_W[i];
    }
    for (int j4 = tid; j4 < ROW_F4; j4 += TPB) {
        unsigned int w = 0;
        #pragma unroll
        for (int u = 0; u < 4; ++u) {
            int jj = 4 * j4 + u;             // 0..263 within a chunk-row
            int tl = jj / 66;                // local step 0..3
            int k  = jj - 66 * tl;           // 0..65
            w |= (unsigned int)(tl * 9 + d_cls3[k]) << (8 * u);
        }
        tabS[j4] = w;
    }
    // single wave: DS pipe in-order; writes above precede reads below (R3-validated)

    // ---- per-chain input projections xr/xz/xh = x @ W + b ----
    float xv[32];
    {
        const float4* xp = reinterpret_cast<const float4*>(x + (size_t)(b0 + tid) * 32);
        #pragma unroll
        for (int i = 0; i < 8; ++i) {
            float4 v = xp[i];
            xv[4*i+0] = v.x; xv[4*i+1] = v.y; xv[4*i+2] = v.z; xv[4*i+3] = v.w;
        }
    }
    float xr[3], xz[3], xh[3];
    #pragma unroll
    for (int j = 0; j < 3; ++j) { xr[j] = w_r_b[j]; xz[j] = w_z_b[j]; xh[j] = w_h_b[j]; }
    #pragma unroll
    for (int i = 0; i < 32; ++i) {
        float xi = xv[i];
        #pragma unroll
        for (int j = 0; j < 3; ++j) {
            xr[j] = fmaf(xi, stage[i*3+j],       xr[j]);
            xz[j] = fmaf(xi, stage[96 + i*3+j],  xz[j]);
            xh[j] = fmaf(xi, stage[192 + i*3+j], xh[j]);
        }
    }

    float W9[9], gb3[3];
    #pragma unroll
    for (int i = 0; i < 9; ++i) W9[i] = gcn_W[i];   // uniform broadcast loads
    #pragma unroll
    for (int j = 0; j < 3; ++j) gb3[j] = gcn_b[j];

    // reduced symmetric-normalized adjacency (3 classes), exact:
    const float M00 = 0.0769230769f;   // 1/13
    const float M01 = 1.1094003925f;   // 4/sqrt(13)
    const float M02 = 0.4961389384f;   // 4/sqrt(65)
    const float M10 = 0.1386750491f;   // 1/(2 sqrt(13))
    const float M11 = 0.75f;
    const float M20 = 0.2480694691f;   // 2/sqrt(65)
    const float M22 = 0.6f;

    float h[9];
    #pragma unroll
    for (int i = 0; i < 9; ++i) h[i] = 0.0f;

    float4* out4 = reinterpret_cast<float4*>(out);

    for (int chunk = 0; chunk < NCHUNK; ++chunk) {
        float* stw = stage + tid * STG_STRIDE;

        #pragma unroll
        for (int s = 0; s < SCH; ++s) {
            float mh[9], gh[9];
            #pragma unroll
            for (int j = 0; j < 3; ++j) {
                mh[j]     = M00 * h[j] + M01 * h[3+j] + M02 * h[6+j];
                mh[3 + j] = M10 * h[j] + M11 * h[3+j];
                mh[6 + j] = M20 * h[j] + M22 * h[6+j];
            }
            #pragma unroll
            for (int c = 0; c < 3; ++c)
                #pragma unroll
                for (int j = 0; j < 3; ++j)
                    gh[c*3+j] = gb3[j] + mh[c*3+0]*W9[j] + mh[c*3+1]*W9[3+j] + mh[c*3+2]*W9[6+j];
            #pragma unroll
            for (int c = 0; c < 3; ++c) {
                #pragma unroll
                for (int j = 0; j < 3; ++j) {
                    float g  = gh[c*3+j];
                    float r  = fast_sigmoid(xr[j] + g);
                    float z  = fast_sigmoid(xz[j] + g);
                    float ht = fast_tanh(xh[j] + r * g);
                    float hv = h[c*3+j];
                    h[c*3+j] = hv + z * (ht - hv);
                }
            }
            #pragma unroll
            for (int q = 0; q < 9; ++q) stw[s*9 + q] = h[q];
        }
        // no barrier: single-wave block, in-order DS (R3-validated)

        // ---- batched expansion: gather ALL 9 f4 into static regs, THEN store ----
        // (maximizes stores-in-flight per wave: data regs all live, no recycling)
        const int cbase = chunk * ROW_F4;
        float4 vv[GITERS];
        #pragma unroll
        for (int i = 0; i < GITERS; ++i) {
            int f  = i * TPB + tid;              // 0..575
            int fi = (f < F4_PER_REP) ? f : 0;   // clamp; garbage discarded
            int rl = fi / ROW_F4;                // 0..7
            int j4 = fi - rl * ROW_F4;           // 0..65
            unsigned int tw = tabS[j4];
            const float* row = stage + (row0 + rl) * STG_STRIDE;
            vv[i].x = row[tw & 255u];
            vv[i].y = row[(tw >> 8)  & 255u];
            vv[i].z = row[(tw >> 16) & 255u];
            vv[i].w = row[tw >> 24];
        }
        #pragma unroll
        for (int i = 0; i < GITERS; ++i) {
            int f = i * TPB + tid;
            if (f < F4_PER_REP) {
                int rl = f / ROW_F4;
                int j4 = f - rl * ROW_F4;
                out4[(size_t)(b0 + row0 + rl) * OUT_ROW_F4 + cbase + j4] = vv[i];
            }
        }
    }
}

extern "C" void kernel_launch(void* const* d_in, const int* in_sizes, int n_in,
                              void* d_out, int out_size, void* d_ws, size_t ws_size,
                              hipStream_t stream) {
    const float* xp     = (const float*)d_in[0];
    const float* w_r_W  = (const float*)d_in[1];
    const float* w_r_b  = (const float*)d_in[2];
    const float* w_z_W  = (const float*)d_in[3];
    const float* w_z_b  = (const float*)d_in[4];
    const float* w_h_W  = (const float*)d_in[5];
    const float* w_h_b  = (const float*)d_in[6];
    const float* gcn_W  = (const float*)d_in[7];
    const float* gcn_b  = (const float*)d_in[8];
    float* outp = (float*)d_out;

    gcgru_fused<<<GRID, TPB, 0, stream>>>(xp, w_r_W, w_r_b, w_z_W, w_z_b,
                                          w_h_W, w_h_b, gcn_W, gcn_b, outp);
}

// Round 8
// 496.431 us; speedup vs baseline: 1.1706x; 1.0022x over previous
//
#include <hip/hip_runtime.h>

// GraphConvGRU: B=16384, IN=32, HID=3, N=22 nodes, T=100 steps.
// Graph collapses to 3 node-equivalence classes -> per-chain state = 9 floats,
// reduced 3x3 adjacency (verified; R0-R3,R6,R7 passed, absmax 3.9e-3).
//
// R8 = R7 + NONTEMPORAL output stores (single-variable A/B).
//   Kernel time is ~210us (2.2 TB/s) invariant across run length (0.5-2.6KB),
//   grid (64-2048 blocks), barriers, ownership, stores-in-flight (3-9).
//   Issue-side arithmetic can't reach 210us -> store-path backpressure.
//   Hypothesis: plain stores write-allocate in per-XCD L2; scattered 1KB
//   runs from 2048 waves -> temporally scattered dirty-line writebacks ->
//   ~2.2 TB/s. The harness fill (6 TB/s) evicts near-sequentially.
//   nt stores bypass L2 allocate -> stream directly. If unchanged, the
//   limiter is DRAM-row scatter -> R9 restructures to a dense global sweep.

#define TPB 64
#define REP 8
#define RPW (TPB / REP)             // 8 rows stored per replica
#define NGRP (16384 / TPB)          // 256 chain-groups
#define GRID (NGRP * REP)           // 2048 blocks
#define T_TOTAL 100
#define SCH 4                       // steps per chunk
#define NCHUNK (T_TOTAL / SCH)      // 25
#define ROW_F4 (SCH * 66 / 4)       // 66 f4 per (row, chunk)
#define STG_STRIDE (SCH * 9 + 1)    // 37 floats per thread-row (odd: 2 lanes/bank)
#define STG_SZ (TPB * STG_STRIDE)   // 2368 floats = 9.25 KB
#define F4_PER_REP (RPW * ROW_F4)   // 528 f4 per replica per chunk
#define GITERS ((F4_PER_REP + TPB - 1) / TPB)   // 9
#define OUT_ROW_F4 1650

typedef float f32x4 __attribute__((ext_vector_type(4)));

#if __has_builtin(__builtin_amdgcn_exp2f)
#define EXP2F __builtin_amdgcn_exp2f
#else
#define EXP2F exp2f
#endif
#if __has_builtin(__builtin_amdgcn_rcpf)
#define RCPF __builtin_amdgcn_rcpf
#else
#define RCPF(x) (1.0f / (x))
#endif

static __device__ __forceinline__ float fast_sigmoid(float x) {
    float e = EXP2F(-1.44269504f * x);
    return RCPF(1.0f + e);
}
static __device__ __forceinline__ float fast_tanh(float x) {
    float e = EXP2F(2.88539008f * x);          // exp(2x)
    return 1.0f - 2.0f * RCPF(1.0f + e);
}

// cls3[k] = class(node k/3)*3 + k%3 for k in [0,66)
__device__ const unsigned char d_cls3[66] = {
    0,1,2, 3,4,5, 3,4,5, 6,7,8, 3,4,5, 3,4,5, 6,7,8, 3,4,5, 3,4,5,
    0,1,2, 3,4,5, 3,4,5, 6,7,8, 3,4,5, 3,4,5, 6,7,8, 3,4,5, 3,4,5,
    3,4,5, 3,4,5, 3,4,5, 3,4,5
};

__global__ __launch_bounds__(TPB) void gcgru_fused(
    const float* __restrict__ x,
    const float* __restrict__ w_r_W, const float* __restrict__ w_r_b,
    const float* __restrict__ w_z_W, const float* __restrict__ w_z_b,
    const float* __restrict__ w_h_W, const float* __restrict__ w_h_b,
    const float* __restrict__ gcn_W, const float* __restrict__ gcn_b,
    float* __restrict__ out)
{
    __shared__ float stage[STG_SZ];         // weights during init, then states
    __shared__ unsigned int tabS[ROW_F4];   // 66 packed per-f4 state indices

    const int tid  = threadIdx.x;           // 0..63, chain within group
    const int rep  = blockIdx.x & (REP - 1);
    const int b0   = (blockIdx.x >> 3) * TPB;
    const int row0 = rep * RPW;             // first row this replica stores

    // ---- init: weights into stage[0..287] (aliased; overwritten after projection) ----
    for (int i = tid; i < 96; i += TPB) {
        stage[i]       = w_r_W[i];
        stage[96 + i]  = w_z_W[i];
        stage[192 + i] = w_h_W[i];
    }
    for (int j4 = tid; j4 < ROW_F4; j4 += TPB) {
        unsigned int w = 0;
        #pragma unroll
        for (int u = 0; u < 4; ++u) {
            int jj = 4 * j4 + u;             // 0..263 within a chunk-row
            int tl = jj / 66;                // local step 0..3
            int k  = jj - 66 * tl;           // 0..65
            w |= (unsigned int)(tl * 9 + d_cls3[k]) << (8 * u);
        }
        tabS[j4] = w;
    }
    // single wave: DS pipe in-order; writes above precede reads below (R3-validated)

    // ---- per-chain input projections xr/xz/xh = x @ W + b ----
    float xv[32];
    {
        const float4* xp = reinterpret_cast<const float4*>(x + (size_t)(b0 + tid) * 32);
        #pragma unroll
        for (int i = 0; i < 8; ++i) {
            float4 v = xp[i];
            xv[4*i+0] = v.x; xv[4*i+1] = v.y; xv[4*i+2] = v.z; xv[4*i+3] = v.w;
        }
    }
    float xr[3], xz[3], xh[3];
    #pragma unroll
    for (int j = 0; j < 3; ++j) { xr[j] = w_r_b[j]; xz[j] = w_z_b[j]; xh[j] = w_h_b[j]; }
    #pragma unroll
    for (int i = 0; i < 32; ++i) {
        float xi = xv[i];
        #pragma unroll
        for (int j = 0; j < 3; ++j) {
            xr[j] = fmaf(xi, stage[i*3+j],       xr[j]);
            xz[j] = fmaf(xi, stage[96 + i*3+j],  xz[j]);
            xh[j] = fmaf(xi, stage[192 + i*3+j], xh[j]);
        }
    }

    float W9[9], gb3[3];
    #pragma unroll
    for (int i = 0; i < 9; ++i) W9[i] = gcn_W[i];   // uniform broadcast loads
    #pragma unroll
    for (int j = 0; j < 3; ++j) gb3[j] = gcn_b[j];

    // reduced symmetric-normalized adjacency (3 classes), exact:
    const float M00 = 0.0769230769f;   // 1/13
    const float M01 = 1.1094003925f;   // 4/sqrt(13)
    const float M02 = 0.4961389384f;   // 4/sqrt(65)
    const float M10 = 0.1386750491f;   // 1/(2 sqrt(13))
    const float M11 = 0.75f;
    const float M20 = 0.2480694691f;   // 2/sqrt(65)
    const float M22 = 0.6f;

    float h[9];
    #pragma unroll
    for (int i = 0; i < 9; ++i) h[i] = 0.0f;

    f32x4* out4 = reinterpret_cast<f32x4*>(out);

    for (int chunk = 0; chunk < NCHUNK; ++chunk) {
        float* stw = stage + tid * STG_STRIDE;

        #pragma unroll
        for (int s = 0; s < SCH; ++s) {
            float mh[9], gh[9];
            #pragma unroll
            for (int j = 0; j < 3; ++j) {
                mh[j]     = M00 * h[j] + M01 * h[3+j] + M02 * h[6+j];
                mh[3 + j] = M10 * h[j] + M11 * h[3+j];
                mh[6 + j] = M20 * h[j] + M22 * h[6+j];
            }
            #pragma unroll
            for (int c = 0; c < 3; ++c)
                #pragma unroll
                for (int j = 0; j < 3; ++j)
                    gh[c*3+j] = gb3[j] + mh[c*3+0]*W9[j] + mh[c*3+1]*W9[3+j] + mh[c*3+2]*W9[6+j];
            #pragma unroll
            for (int c = 0; c < 3; ++c) {
                #pragma unroll
                for (int j = 0; j < 3; ++j) {
                    float g  = gh[c*3+j];
                    float r  = fast_sigmoid(xr[j] + g);
                    float z  = fast_sigmoid(xz[j] + g);
                    float ht = fast_tanh(xh[j] + r * g);
                    float hv = h[c*3+j];
                    h[c*3+j] = hv + z * (ht - hv);
                }
            }
            #pragma unroll
            for (int q = 0; q < 9; ++q) stw[s*9 + q] = h[q];
        }
        // no barrier: single-wave block, in-order DS (R3-validated)

        // ---- batched expansion: gather ALL 9 f4 into static regs, THEN store ----
        const int cbase = chunk * ROW_F4;
        f32x4 vv[GITERS];
        #pragma unroll
        for (int i = 0; i < GITERS; ++i) {
            int f  = i * TPB + tid;              // 0..575
            int fi = (f < F4_PER_REP) ? f : 0;   // clamp; garbage discarded
            int rl = fi / ROW_F4;                // 0..7
            int j4 = fi - rl * ROW_F4;           // 0..65
            unsigned int tw = tabS[j4];
            const float* row = stage + (row0 + rl) * STG_STRIDE;
            vv[i].x = row[tw & 255u];
            vv[i].y = row[(tw >> 8)  & 255u];
            vv[i].z = row[(tw >> 16) & 255u];
            vv[i].w = row[tw >> 24];
        }
        #pragma unroll
        for (int i = 0; i < GITERS; ++i) {
            int f = i * TPB + tid;
            if (f < F4_PER_REP) {
                int rl = f / ROW_F4;
                int j4 = f - rl * ROW_F4;
                // NONTEMPORAL: bypass L2 write-allocate; stream to memory.
                __builtin_nontemporal_store(
                    vv[i], out4 + (size_t)(b0 + row0 + rl) * OUT_ROW_F4 + cbase + j4);
            }
        }
    }
}

extern "C" void kernel_launch(void* const* d_in, const int* in_sizes, int n_in,
                              void* d_out, int out_size, void* d_ws, size_t ws_size,
                              hipStream_t stream) {
    const float* xp     = (const float*)d_in[0];
    const float* w_r_W  = (const float*)d_in[1];
    const float* w_r_b  = (const float*)d_in[2];
    const float* w_z_W  = (const float*)d_in[3];
    const float* w_z_b  = (const float*)d_in[4];
    const float* w_h_W  = (const float*)d_in[5];
    const float* w_h_b  = (const float*)d_in[6];
    const float* gcn_W  = (const float*)d_in[7];
    const float* gcn_b  = (const float*)d_in[8];
    float* outp = (float*)d_out;

    gcgru_fused<<<GRID, TPB, 0, stream>>>(xp, w_r_W, w_r_b, w_z_W, w_z_b,
                                          w_h_W, w_h_b, gcn_W, gcn_b, outp);
}